// Round 1
// baseline (689.638 us; speedup 1.0000x reference)
//
#include <hip/hip_runtime.h>
#include <hip/hip_bf16.h>

#define N_EDGES_C 1000000
#define EDGE_DIM_C 64
#define NODE_DIM_C 64
#define IN_DIM_C   192
#define HID_C      256
#define XPAD 200   // padded bf16 elems per X row (192 + 8) -> 400B rows, 16B aligned
#define HPAD 264   // padded bf16 elems per H row (256 + 8) -> 528B rows, 16B aligned

typedef __attribute__((ext_vector_type(8))) short  short8;
typedef __attribute__((ext_vector_type(4))) float  f32x4;

__device__ __forceinline__ unsigned short f2bf(float f) {
    union { float f; unsigned u; } v; v.f = f;
    unsigned u = v.u;
    u += 0x7fffu + ((u >> 16) & 1u);   // round-to-nearest-even
    return (unsigned short)(u >> 16);
}

// Pre-transpose + convert weights: W1[192][256] -> W1T bf16 [256][192],
// W2[256][256] -> W2T bf16 [256][256]. Tiny (115K elems), runs once per launch.
__global__ void prep_weights_kernel(const float* __restrict__ W1,
                                    const float* __restrict__ W2,
                                    unsigned short* __restrict__ W1T,
                                    unsigned short* __restrict__ W2T) {
    int tid = blockIdx.x * 256 + threadIdx.x;
    if (tid < IN_DIM_C * HID_C) {
        int n = tid / IN_DIM_C, k = tid - n * IN_DIM_C;
        W1T[tid] = f2bf(W1[k * HID_C + n]);
    } else {
        int t2 = tid - IN_DIM_C * HID_C;
        if (t2 < HID_C * HID_C) {
            int o = t2 / HID_C, k = t2 - o * HID_C;
            W2T[t2] = f2bf(W2[k * HID_C + o]);
        }
    }
}

// One block = 64 edges. 4 waves; wave w owns feature slice [w*64, w*64+64).
// Layer 1: Hs[m][n] = relu(sum_k X[m][k] * W1[k][n] + b1[n]) computed as
//   D[n][m] = mfma(A=W1T rows, B=X rows)  (16x16x32 bf16, fp32 acc)
// Layer 2: out[m][o] = sum_k Hs[m][k] * W2[k][o] + b2[o], same transposed form.
__global__ __launch_bounds__(256, 2) void edge_mlp_kernel(
    const float* __restrict__ E, const float* __restrict__ V,
    const int* __restrict__ srcI, const int* __restrict__ dstI,
    const unsigned short* __restrict__ W1T, const float* __restrict__ b1,
    const unsigned short* __restrict__ W2T, const float* __restrict__ b2,
    float* __restrict__ out)
{
    __shared__ unsigned short Xs[64 * XPAD];
    __shared__ unsigned short Hs[64 * HPAD];
    __shared__ int sidx[64];
    __shared__ int didx[64];

    const int tid  = threadIdx.x;
    const int base = blockIdx.x * 64;

    // --- preload gather indices ---
    if (tid < 64)        sidx[tid]      = srcI[base + tid];
    else if (tid < 128)  didx[tid - 64] = dstI[base + tid - 64];

    // --- stage E (64 rows x 64 fp32, perfectly coalesced float4) ---
#pragma unroll
    for (int i = 0; i < 4; ++i) {
        int idx = tid + i * 256;        // 0..1023 float4s
        int r = idx >> 4, c4 = idx & 15;
        float4 v = *reinterpret_cast<const float4*>(
            E + (size_t)(base + r) * EDGE_DIM_C + c4 * 4);
        ushort4 b;
        b.x = f2bf(v.x); b.y = f2bf(v.y); b.z = f2bf(v.z); b.w = f2bf(v.w);
        *reinterpret_cast<ushort4*>(&Xs[r * XPAD + c4 * 4]) = b;
    }
    __syncthreads();   // indices ready

    // --- stage V[src], V[dst] gathers (64 rows x 128 fp32) ---
#pragma unroll
    for (int i = 0; i < 8; ++i) {
        int idx = tid + i * 256;        // 0..2047 float4s
        int r = idx >> 5, c4 = idx & 31;
        int col = c4 * 4;
        const float* vp = (col < 64)
            ? (V + (size_t)sidx[r] * NODE_DIM_C + col)
            : (V + (size_t)didx[r] * NODE_DIM_C + (col - 64));
        float4 v = *reinterpret_cast<const float4*>(vp);
        ushort4 b;
        b.x = f2bf(v.x); b.y = f2bf(v.y); b.z = f2bf(v.z); b.w = f2bf(v.w);
        *reinterpret_cast<ushort4*>(&Xs[r * XPAD + 64 + col]) = b;
    }
    __syncthreads();

    const int w  = tid >> 6;    // wave id 0..3
    const int l  = tid & 63;
    const int lm = l & 15;      // A-row / B-col / D-col lane index
    const int lg = l >> 4;      // k-group / D-row group

    // ---------------- Layer 1 ----------------
    f32x4 acc[4][4];            // [ntile][mtile]
#pragma unroll
    for (int a = 0; a < 4; ++a)
#pragma unroll
        for (int b = 0; b < 4; ++b)
            acc[a][b] = (f32x4){0.f, 0.f, 0.f, 0.f};

    const unsigned short* w1base = W1T + (size_t)(w * 64) * IN_DIM_C;
#pragma unroll
    for (int kb = 0; kb < 6; ++kb) {
        short8 aw[4], bx[4];
#pragma unroll
        for (int nt = 0; nt < 4; ++nt)
            aw[nt] = *reinterpret_cast<const short8*>(
                w1base + (nt * 16 + lm) * IN_DIM_C + kb * 32 + lg * 8);
#pragma unroll
        for (int mt = 0; mt < 4; ++mt)
            bx[mt] = *reinterpret_cast<const short8*>(
                &Xs[(mt * 16 + lm) * XPAD + kb * 32 + lg * 8]);
#pragma unroll
        for (int nt = 0; nt < 4; ++nt)
#pragma unroll
            for (int mt = 0; mt < 4; ++mt)
                acc[nt][mt] = __builtin_amdgcn_mfma_f32_16x16x32_bf16(
                    aw[nt], bx[mt], acc[nt][mt], 0, 0, 0);
    }

    // epilogue 1: + b1, relu, bf16, store H to LDS (4 consecutive n -> b64 write)
#pragma unroll
    for (int nt = 0; nt < 4; ++nt) {
        int n0 = w * 64 + nt * 16 + lg * 4;
        float4 bv = *reinterpret_cast<const float4*>(b1 + n0);
#pragma unroll
        for (int mt = 0; mt < 4; ++mt) {
            f32x4 a = acc[nt][mt];
            ushort4 hb;
            hb.x = f2bf(fmaxf(a[0] + bv.x, 0.f));
            hb.y = f2bf(fmaxf(a[1] + bv.y, 0.f));
            hb.z = f2bf(fmaxf(a[2] + bv.z, 0.f));
            hb.w = f2bf(fmaxf(a[3] + bv.w, 0.f));
            int m = mt * 16 + lm;
            *reinterpret_cast<ushort4*>(&Hs[m * HPAD + n0]) = hb;
        }
    }
    __syncthreads();

    // ---------------- Layer 2 ----------------
#pragma unroll
    for (int a = 0; a < 4; ++a)
#pragma unroll
        for (int b = 0; b < 4; ++b)
            acc[a][b] = (f32x4){0.f, 0.f, 0.f, 0.f};

    const unsigned short* w2base = W2T + (size_t)(w * 64) * HID_C;
#pragma unroll
    for (int kb = 0; kb < 8; ++kb) {
        short8 aw[4], bh[4];
#pragma unroll
        for (int ot = 0; ot < 4; ++ot)
            aw[ot] = *reinterpret_cast<const short8*>(
                w2base + (ot * 16 + lm) * HID_C + kb * 32 + lg * 8);
#pragma unroll
        for (int mt = 0; mt < 4; ++mt)
            bh[mt] = *reinterpret_cast<const short8*>(
                &Hs[(mt * 16 + lm) * HPAD + kb * 32 + lg * 8]);
#pragma unroll
        for (int ot = 0; ot < 4; ++ot)
#pragma unroll
            for (int mt = 0; mt < 4; ++mt)
                acc[ot][mt] = __builtin_amdgcn_mfma_f32_16x16x32_bf16(
                    aw[ot], bh[mt], acc[ot][mt], 0, 0, 0);
    }

    // epilogue 2: + b2, coalesced float4 store (4 consecutive o per lane)
#pragma unroll
    for (int ot = 0; ot < 4; ++ot) {
        int o0 = w * 64 + ot * 16 + lg * 4;
        float4 bv = *reinterpret_cast<const float4*>(b2 + o0);
#pragma unroll
        for (int mt = 0; mt < 4; ++mt) {
            f32x4 a = acc[ot][mt];
            float4 r;
            r.x = a[0] + bv.x;
            r.y = a[1] + bv.y;
            r.z = a[2] + bv.z;
            r.w = a[3] + bv.w;
            size_t m = (size_t)(base + mt * 16 + lm);
            *reinterpret_cast<float4*>(out + m * HID_C + o0) = r;
        }
    }
}

extern "C" void kernel_launch(void* const* d_in, const int* in_sizes, int n_in,
                              void* d_out, int out_size, void* d_ws, size_t ws_size,
                              hipStream_t stream) {
    const float* E  = (const float*)d_in[0];
    const float* V  = (const float*)d_in[1];
    const int*   ei = (const int*)d_in[2];   // [2][N_EDGES] int32
    const float* W1 = (const float*)d_in[3];
    const float* b1 = (const float*)d_in[4];
    const float* W2 = (const float*)d_in[5];
    const float* b2 = (const float*)d_in[6];
    float* out = (float*)d_out;

    unsigned short* W1T = (unsigned short*)d_ws;                 // 256*192 bf16
    unsigned short* W2T = W1T + IN_DIM_C * HID_C;                // 256*256 bf16

    const int prep_total = IN_DIM_C * HID_C + HID_C * HID_C;     // 114688
    prep_weights_kernel<<<(prep_total + 255) / 256, 256, 0, stream>>>(W1, W2, W1T, W2T);

    const int nblocks = N_EDGES_C / 64;                          // 15625
    edge_mlp_kernel<<<nblocks, 256, 0, stream>>>(
        E, V, ei, ei + N_EDGES_C, W1T, b1, W2T, b2, out);
}